// Round 11
// baseline (260.154 us; speedup 1.0000x reference)
//
#include <hip/hip_runtime.h>

#define N_NODES 50000
#define N_EDGES 800000
#define D_HID   128

typedef unsigned int uint;
typedef unsigned short ushort;
typedef __attribute__((ext_vector_type(8))) short short8;
typedef __attribute__((ext_vector_type(4))) float f32x4;

#define SCAN_NB ((N_NODES + 255) / 256)   // 196
#define NB       196                       // dst buckets of 256 nodes
#define CAP      6144                      // per-bucket ebuf capacity
#define P1_BLOCKS 200
#define P1_CHUNK  4000                     // 200 * 4000 = 800000 exactly

// ---------------- P1: partition edges into dst-range buckets ----------------
__global__ __launch_bounds__(256) void part_k(const int* __restrict__ src,
                                              const int* __restrict__ dst,
                                              int* __restrict__ bcur,
                                              int2* __restrict__ ebuf, int e) {
    __shared__ int hist[NB];
    __shared__ int base[NB];
    int tid = threadIdx.x;
    if (tid < NB) hist[tid] = 0;
    __syncthreads();

    int e0 = blockIdx.x * P1_CHUNK;
    int2 ed[16];
    bool val[16];
#pragma unroll
    for (int i = 0; i < 16; ++i) {
        int o = i * 256 + tid;
        int idx = e0 + o;
        val[i] = (o < P1_CHUNK) && (idx < e);
        if (val[i]) {
            ed[i] = make_int2(src[idx], dst[idx]);
            atomicAdd(&hist[ed[i].y >> 8], 1);
        }
    }
    __syncthreads();
    if (tid < NB && hist[tid] > 0) base[tid] = atomicAdd(&bcur[tid], hist[tid]);
    __syncthreads();
    if (tid < NB) hist[tid] = 0;
    __syncthreads();
#pragma unroll
    for (int i = 0; i < 16; ++i) {
        if (val[i]) {
            int bk = ed[i].y >> 8;
            int o  = base[bk] + atomicAdd(&hist[bk], 1);
            if (o < CAP) ebuf[(size_t)bk * CAP + o] = ed[i];
        }
    }
}

// ---------------- P2: per-bucket degree count (LDS atomics) ----------------
__global__ __launch_bounds__(256) void bucket_cnt_k(const int2* __restrict__ ebuf,
                                                    const int* __restrict__ bcnt,
                                                    int* __restrict__ cnt, int n) {
    __shared__ int c[256];
    int b = blockIdx.x, tid = threadIdx.x;
    c[tid] = 0;
    __syncthreads();
    int m = bcnt[b]; if (m > CAP) m = CAP;
    for (int i = tid; i < m; i += 256)
        atomicAdd(&c[ebuf[(size_t)b * CAP + i].y & 255], 1);
    __syncthreads();
    int node = b * 256 + tid;
    if (node < n) cnt[node] = c[tid];
}

// ---------------- 3-phase multi-block exclusive scan ----------------
__global__ void bsum_k(const int* __restrict__ cnt, int* __restrict__ bsum, int n) {
    int i = blockIdx.x * 256 + threadIdx.x;
    int v = (i < n) ? cnt[i] : 0;
#pragma unroll
    for (int off = 32; off; off >>= 1) v += __shfl_down(v, off, 64);
    __shared__ int ws[4];
    int lane = threadIdx.x & 63, w = threadIdx.x >> 6;
    if (lane == 0) ws[w] = v;
    __syncthreads();
    if (threadIdx.x == 0) bsum[blockIdx.x] = ws[0] + ws[1] + ws[2] + ws[3];
}

__global__ void bscan_k(const int* __restrict__ bsum, int* __restrict__ boff,
                        int* __restrict__ row_ptr_end, int nb) {
    __shared__ int s[256];
    int t = threadIdx.x;
    int v = (t < nb) ? bsum[t] : 0;
    s[t] = v;
    __syncthreads();
    for (int off = 1; off < 256; off <<= 1) {
        int u = (t >= off) ? s[t - off] : 0;
        __syncthreads();
        s[t] += u;
        __syncthreads();
    }
    if (t < nb) boff[t] = s[t] - v;        // exclusive
    if (t == 255) *row_ptr_end = s[255];   // total -> row_ptr[n]
}

// scan + fused degree-norm (dis only; dinv folded away algebraically)
__global__ void scan3_k(const int* __restrict__ cnt, const int* __restrict__ boff,
                        int* __restrict__ row_ptr, float* __restrict__ dis, int n) {
    __shared__ int s[256];
    int i = blockIdx.x * 256 + threadIdx.x;
    int t = threadIdx.x;
    int v = (i < n) ? cnt[i] : 0;
    s[t] = v;
    __syncthreads();
    for (int off = 1; off < 256; off <<= 1) {
        int u = (t >= off) ? s[t - off] : 0;
        __syncthreads();
        s[t] += u;
        __syncthreads();
    }
    if (i < n) {
        row_ptr[i] = boff[blockIdx.x] + s[t] - v;
        dis[i] = rsqrtf((float)v + 1.0f);
    }
}

// ---------------- P3: per-bucket CSR scatter via LDS window (coalesced dump) ----------------
__global__ __launch_bounds__(256) void csr_k(const int2* __restrict__ ebuf,
                                             const int* __restrict__ bcnt,
                                             const int* __restrict__ row_ptr,
                                             int* __restrict__ col, int n) {
    __shared__ int rp_l[257];
    __shared__ int cur[256];
    __shared__ int win[CAP];
    int b = blockIdx.x, tid = threadIdx.x;
    int node0 = b * 256;
    for (int i = tid; i < 257; i += 256) {
        int nd = node0 + i; if (nd > n) nd = n;
        rp_l[i] = row_ptr[nd];
    }
    cur[tid] = 0;
    __syncthreads();
    int base0 = rp_l[0];
    int m = bcnt[b]; if (m > CAP) m = CAP;

    for (int i = tid; i < m; i += 256) {
        int2 ed = ebuf[(size_t)b * CAP + i];
        int ll = ed.y & 255;
        int pos = rp_l[ll] + atomicAdd(&cur[ll], 1) - base0;
        win[pos] = ed.x;
    }
    __syncthreads();
    for (int i = tid; i < m; i += 256) col[base0 + i] = win[i];
}

// ---------------- canonicalize: wave-per-row sort (wide grid) ----------------
__global__ __launch_bounds__(256) void rowsort_k(const int* __restrict__ rp,
                                                 int* __restrict__ col, int n) {
    int node = blockIdx.x * 4 + (threadIdx.x >> 6);
    if (node >= n) return;
    int lane = threadIdx.x & 63;
    int beg = rp[node], end = rp[node + 1];
    int len = end - beg;
    if (len <= 1) return;
    if (len <= 64) {
        int v = (lane < len) ? col[beg + lane] : 0x7fffffff;
#pragma unroll
        for (int k = 2; k <= 64; k <<= 1)
#pragma unroll
            for (int j = k >> 1; j > 0; j >>= 1) {
                int other = __shfl_xor(v, j);
                bool up    = (lane & k) == 0;
                bool small = (lane & j) == 0;
                v = (small == up) ? min(v, other) : max(v, other);
            }
        if (lane < len) col[beg + lane] = v;
    } else if (lane == 0) {     // rare tail: serial insertion sort
        for (int i = beg + 1; i < end; ++i) {
            int key = col[i]; int j = i - 1;
            while (j >= beg && col[j] > key) { col[j + 1] = col[j]; --j; }
            col[j + 1] = key;
        }
    }
}

// ---- fp32 -> bf16 (RTNE) ----
__device__ inline ushort f2bf(float f) {
    unsigned u = __float_as_uint(f);
    unsigned rounding = 0x7fffu + ((u >> 16) & 1u);
    return (ushort)((u + rounding) >> 16);
}
__device__ inline float bf_lo(uint v) { return __uint_as_float(v << 16); }
__device__ inline float bf_hi(uint v) { return __uint_as_float(v & 0xffff0000u); }
__device__ inline short8 cvt8(float4 f0, float4 f1) {
    short8 r;
    r[0] = (short)f2bf(f0.x); r[1] = (short)f2bf(f0.y);
    r[2] = (short)f2bf(f0.z); r[3] = (short)f2bf(f0.w);
    r[4] = (short)f2bf(f1.x); r[5] = (short)f2bf(f1.y);
    r[6] = (short)f2bf(f1.z); r[7] = (short)f2bf(f1.w);
    return r;
}

// ---------------- all three W -> Wt bf16, one launch; also zero hb pad row N ----------------
__global__ void wtrans_all_k(const float* __restrict__ W0, const float* __restrict__ W1,
                             const float* __restrict__ W2, ushort* __restrict__ Wt0,
                             ushort* __restrict__ Wt1, ushort* __restrict__ Wt2,
                             uint* __restrict__ hb_padrow) {
    int i = blockIdx.x * 256 + threadIdx.x;   // 0..65535
    if (i < 64) hb_padrow[i] = 0;             // zero row N of hb (gather target for pad slots)
    const float* W; ushort* Wt; int K, j;
    if (i < 32768)      { W = W0; Wt = Wt0; K = 256; j = i; }
    else if (i < 49152) { W = W1; Wt = Wt1; K = 128; j = i - 32768; }
    else                { W = W2; Wt = Wt2; K = 128; j = i - 49152; }
    int k = j >> 7, n = j & 127;
    Wt[(size_t)n * K + k] = f2bf(W[j]);
}

// ---------------- MFMA GEMM, register-resident B, tile loop + A prefetch ----------------
// Epilogue scales by dis[row]: H holds hs = dis * (A W)  [bf16].
template<int K, bool AF32>
__global__ __launch_bounds__(256, 3) void mfma_gemm_k(const void* __restrict__ Ap,
                                                      const ushort* __restrict__ Bt, // [128][K]
                                                      const float* __restrict__ dis,
                                                      ushort* __restrict__ H,        // [(M+1)][128]
                                                      int M, int ntiles) {
    constexpr int T   = K / 32;
    constexpr int NC  = (K == 128) ? 4 : 2;
    constexpr int RPT = (K == 128) ? 32 : 16;
    int tid = threadIdx.x;
    int w = tid >> 6, l = tid & 63;
    int lr = l & 15, kg = (l >> 4) * 8;
    int rIn   = (K == 128) ? (w >> 1) * 16 : 0;
    int cBase = (K == 128) ? (w & 1) * 64 : w * 32;

    short8 b[NC][T];
#pragma unroll
    for (int c = 0; c < NC; ++c)
#pragma unroll
        for (int t = 0; t < T; ++t)
            b[c][t] = *(const short8*)&Bt[(size_t)(cBase + c * 16 + lr) * K + t * 32 + kg];

    int tile = blockIdx.x;
    if (tile >= ntiles) return;
    const int G = gridDim.x;

    auto loadA = [&](int tl, short8* dst) {
        int rc = tl * RPT + rIn + lr; if (rc >= M) rc = M - 1;
        if constexpr (AF32) {
            const float* A32 = (const float*)Ap;
#pragma unroll
            for (int t = 0; t < T; ++t) {
                float4 f0 = *(const float4*)&A32[(size_t)rc * K + t * 32 + kg];
                float4 f1 = *(const float4*)&A32[(size_t)rc * K + t * 32 + kg + 4];
                dst[t] = cvt8(f0, f1);
            }
        } else {
            const ushort* A16 = (const ushort*)Ap;
#pragma unroll
            for (int t = 0; t < T; ++t)
                dst[t] = *(const short8*)&A16[(size_t)rc * K + t * 32 + kg];
        }
    };

    short8 a[T];
    loadA(tile, a);
    for (; tile < ntiles; tile += G) {
        short8 an[T];
        int nt = tile + G;
        if (nt < ntiles) loadA(nt, an);          // prefetch next tile's A

        f32x4 acc[NC];
#pragma unroll
        for (int c = 0; c < NC; ++c) acc[c] = (f32x4){0.f, 0.f, 0.f, 0.f};
#pragma unroll
        for (int t = 0; t < T; ++t)
#pragma unroll
            for (int c = 0; c < NC; ++c)
                acc[c] = __builtin_amdgcn_mfma_f32_16x16x32_bf16(a[t], b[c][t], acc[c], 0, 0, 0);

        int rs = tile * RPT + rIn + (l >> 4) * 4;
        float dsc[4];
#pragma unroll
        for (int j = 0; j < 4; ++j) dsc[j] = (rs + j < M) ? dis[rs + j] : 0.f;
#pragma unroll
        for (int c = 0; c < NC; ++c)
#pragma unroll
            for (int j = 0; j < 4; ++j) {
                int r = rs + j;
                if (r < M) H[(size_t)r * 128 + cBase + c * 16 + lr] = f2bf(acc[c][j] * dsc[j]);
            }
#pragma unroll
        for (int t = 0; t < T; ++t) a[t] = an[t];
    }
}

// ---------------- aggregate: relu(dis[n]*(sum_e hs[s] + hs[n]) + b) ----------------
// hs is pre-scaled by dis in the GEMM epilogue; pad slots gather the zero row N.
// 8 slots x 4 lane-groups = 32 edges in flight per iteration.
template<bool LAST>
__global__ __launch_bounds__(256) void aggregate_k(const ushort* __restrict__ hs,
                                                   const int* __restrict__ row_ptr,
                                                   const int* __restrict__ col,
                                                   const float* __restrict__ dis,
                                                   const float* __restrict__ bias,
                                                   ushort* __restrict__ act,
                                                   float* __restrict__ out, int n) {
    int node = blockIdx.x * 4 + (threadIdx.x >> 6);
    if (node >= n) return;
    int lane = threadIdx.x & 63;
    int g  = lane >> 4;          // edge-slot group 0..3
    int cl = lane & 15;          // column block: cols [8*cl, 8*cl+8)
    const char* base = (const char*)hs + (cl << 4);

    float ax[8];
#pragma unroll
    for (int j = 0; j < 8; ++j) ax[j] = 0.f;

    int beg = row_ptr[node], end = row_ptr[node + 1];
    for (int e = beg; e < end; e += 32) {
        int s[8];
#pragma unroll
        for (int q = 0; q < 8; ++q) {
            int idx = e + q * 4 + g;
            s[q] = (idx < end) ? col[idx] : N_NODES;   // pad -> zero row
        }
        uint4 u[8];
#pragma unroll
        for (int q = 0; q < 8; ++q)
            u[q] = *(const uint4*)(base + ((size_t)s[q] << 8));
#pragma unroll
        for (int q = 0; q < 8; ++q) {
            ax[0] += bf_lo(u[q].x); ax[1] += bf_hi(u[q].x);
            ax[2] += bf_lo(u[q].y); ax[3] += bf_hi(u[q].y);
            ax[4] += bf_lo(u[q].z); ax[5] += bf_hi(u[q].z);
            ax[6] += bf_lo(u[q].w); ax[7] += bf_hi(u[q].w);
        }
    }
#pragma unroll
    for (int j = 0; j < 8; ++j) {
        ax[j] += __shfl_xor(ax[j], 16);
        ax[j] += __shfl_xor(ax[j], 32);
    }
    if (g == 0) {
        float dn = dis[node];
        uint4 un = *(const uint4*)(base + ((size_t)node << 8));
        float hsn[8] = {bf_lo(un.x), bf_hi(un.x), bf_lo(un.y), bf_hi(un.y),
                        bf_lo(un.z), bf_hi(un.z), bf_lo(un.w), bf_hi(un.w)};
        int c0 = cl * 8;
        float4 bv0 = *(const float4*)&bias[c0];
        float4 bv1 = *(const float4*)&bias[c0 + 4];
        float bb[8] = {bv0.x, bv0.y, bv0.z, bv0.w, bv1.x, bv1.y, bv1.z, bv1.w};
        float o[8];
#pragma unroll
        for (int j = 0; j < 8; ++j)
            o[j] = fmaxf((ax[j] + hsn[j]) * dn + bb[j], 0.f);
        if (LAST) {
            *(float4*)&out[(size_t)node * D_HID + c0]     = make_float4(o[0], o[1], o[2], o[3]);
            *(float4*)&out[(size_t)node * D_HID + c0 + 4] = make_float4(o[4], o[5], o[6], o[7]);
        } else {
            uint4 p;
            p.x = (uint)f2bf(o[0]) | ((uint)f2bf(o[1]) << 16);
            p.y = (uint)f2bf(o[2]) | ((uint)f2bf(o[3]) << 16);
            p.z = (uint)f2bf(o[4]) | ((uint)f2bf(o[5]) << 16);
            p.w = (uint)f2bf(o[6]) | ((uint)f2bf(o[7]) << 16);
            *(uint4*)((char*)act + ((size_t)node << 8) + (cl << 4)) = p;
        }
    }
}

extern "C" void kernel_launch(void* const* d_in, const int* in_sizes, int n_in,
                              void* d_out, int out_size, void* d_ws, size_t ws_size,
                              hipStream_t stream) {
    const float* x  = (const float*)d_in[0];
    const int*   ei = (const int*)d_in[1];
    const float* W0 = (const float*)d_in[2];
    const float* b0 = (const float*)d_in[3];
    const float* W1 = (const float*)d_in[4];
    const float* b1 = (const float*)d_in[5];
    const float* W2 = (const float*)d_in[6];
    const float* b2 = (const float*)d_in[7];
    float* out = (float*)d_out;

    const int N = N_NODES, E = N_EDGES;
    const int* src = ei;
    const int* dst = ei + E;

    char* w = (char*)d_ws;
    size_t off = 0;
    auto alloc = [&](size_t bytes) {
        size_t o = off;
        off += (bytes + 255) & ~(size_t)255;
        return o;
    };
    int*    cnt    = (int*)(w + alloc((size_t)N * 4));
    int*    bcur   = (int*)(w + alloc((size_t)NB * 4));
    float*  dis    = (float*)(w + alloc((size_t)N * 4));
    int*    rp     = (int*)(w + alloc((size_t)(N + 1) * 4));
    int*    bsum   = (int*)(w + alloc((size_t)SCAN_NB * 4));
    int*    boff   = (int*)(w + alloc((size_t)SCAN_NB * 4));
    int*    col    = (int*)(w + alloc((size_t)E * 4));
    int2*   ebuf   = (int2*)(w + alloc((size_t)NB * CAP * 8));
    ushort* hb     = (ushort*)(w + alloc((size_t)(N + 1) * D_HID * 2));  // +1 zero pad row
    ushort* act    = (ushort*)(w + alloc((size_t)N * D_HID * 2));
    ushort* Wt0    = (ushort*)(w + alloc((size_t)128 * 256 * 2));
    ushort* Wt1    = (ushort*)(w + alloc((size_t)128 * 128 * 2));
    ushort* Wt2    = (ushort*)(w + alloc((size_t)128 * 128 * 2));
    (void)ws_size; (void)n_in; (void)in_sizes; (void)out_size;

    hipMemsetAsync(bcur, 0, (size_t)NB * 4, stream);

    part_k<<<P1_BLOCKS, 256, 0, stream>>>(src, dst, bcur, ebuf, E);
    bucket_cnt_k<<<NB, 256, 0, stream>>>(ebuf, bcur, cnt, N);
    bsum_k<<<SCAN_NB, 256, 0, stream>>>(cnt, bsum, N);
    bscan_k<<<1, 256, 0, stream>>>(bsum, boff, rp + N, SCAN_NB);
    scan3_k<<<SCAN_NB, 256, 0, stream>>>(cnt, boff, rp, dis, N);
    csr_k<<<NB, 256, 0, stream>>>(ebuf, bcur, rp, col, N);
    rowsort_k<<<(N + 3) / 4, 256, 0, stream>>>(rp, col, N);   // canonical order

    wtrans_all_k<<<256, 256, 0, stream>>>(W0, W1, W2, Wt0, Wt1, Wt2,
                                          (uint*)(hb + (size_t)N * D_HID));

    const int GG = 768;
    int nt256 = (N + 15) / 16;   // 3125
    int nt128 = (N + 31) / 32;   // 1563
    int agg_grid = (N + 3) / 4;

    // layer 0
    mfma_gemm_k<256, true><<<GG, 256, 0, stream>>>(x, Wt0, dis, hb, N, nt256);
    aggregate_k<false><<<agg_grid, 256, 0, stream>>>(hb, rp, col, dis, b0, act, out, N);
    // layer 1
    mfma_gemm_k<128, false><<<GG, 256, 0, stream>>>(act, Wt1, dis, hb, N, nt128);
    aggregate_k<false><<<agg_grid, 256, 0, stream>>>(hb, rp, col, dis, b1, act, out, N);
    // layer 2
    mfma_gemm_k<128, false><<<GG, 256, 0, stream>>>(act, Wt2, dis, hb, N, nt128);
    aggregate_k<true><<<agg_grid, 256, 0, stream>>>(hb, rp, col, dis, b2, act, out, N);
}

// Round 12
// 232.254 us; speedup vs baseline: 1.1201x; 1.1201x over previous
//
#include <hip/hip_runtime.h>

#define N_NODES 50000
#define N_EDGES 800000
#define D_HID   128

typedef unsigned int uint;
typedef unsigned short ushort;
typedef __attribute__((ext_vector_type(8))) short short8;
typedef __attribute__((ext_vector_type(4))) float f32x4;

#define SCAN_NB ((N_NODES + 255) / 256)   // 196
#define NB       196                       // dst buckets of 256 nodes
#define CAP      6144                      // per-bucket ebuf capacity
#define P1_BLOCKS 200
#define P1_CHUNK  4000                     // 200 * 4000 = 800000 exactly

// ---------------- P1: partition edges into dst-range buckets ----------------
__global__ __launch_bounds__(256) void part_k(const int* __restrict__ src,
                                              const int* __restrict__ dst,
                                              int* __restrict__ bcur,
                                              int2* __restrict__ ebuf, int e) {
    __shared__ int hist[NB];
    __shared__ int base[NB];
    int tid = threadIdx.x;
    if (tid < NB) hist[tid] = 0;
    __syncthreads();

    int e0 = blockIdx.x * P1_CHUNK;
    int2 ed[16];
    bool val[16];
#pragma unroll
    for (int i = 0; i < 16; ++i) {
        int o = i * 256 + tid;
        int idx = e0 + o;
        val[i] = (o < P1_CHUNK) && (idx < e);
        if (val[i]) {
            ed[i] = make_int2(src[idx], dst[idx]);
            atomicAdd(&hist[ed[i].y >> 8], 1);
        }
    }
    __syncthreads();
    if (tid < NB && hist[tid] > 0) base[tid] = atomicAdd(&bcur[tid], hist[tid]);
    __syncthreads();
    if (tid < NB) hist[tid] = 0;
    __syncthreads();
#pragma unroll
    for (int i = 0; i < 16; ++i) {
        if (val[i]) {
            int bk = ed[i].y >> 8;
            int o  = base[bk] + atomicAdd(&hist[bk], 1);
            if (o < CAP) ebuf[(size_t)bk * CAP + o] = ed[i];
        }
    }
}

// ---------------- P2: per-bucket degree count (LDS atomics) ----------------
__global__ __launch_bounds__(256) void bucket_cnt_k(const int2* __restrict__ ebuf,
                                                    const int* __restrict__ bcnt,
                                                    int* __restrict__ cnt, int n) {
    __shared__ int c[256];
    int b = blockIdx.x, tid = threadIdx.x;
    c[tid] = 0;
    __syncthreads();
    int m = bcnt[b]; if (m > CAP) m = CAP;
    for (int i = tid; i < m; i += 256)
        atomicAdd(&c[ebuf[(size_t)b * CAP + i].y & 255], 1);
    __syncthreads();
    int node = b * 256 + tid;
    if (node < n) cnt[node] = c[tid];
}

// ---------------- 3-phase multi-block exclusive scan ----------------
__global__ void bsum_k(const int* __restrict__ cnt, int* __restrict__ bsum, int n) {
    int i = blockIdx.x * 256 + threadIdx.x;
    int v = (i < n) ? cnt[i] : 0;
#pragma unroll
    for (int off = 32; off; off >>= 1) v += __shfl_down(v, off, 64);
    __shared__ int ws[4];
    int lane = threadIdx.x & 63, w = threadIdx.x >> 6;
    if (lane == 0) ws[w] = v;
    __syncthreads();
    if (threadIdx.x == 0) bsum[blockIdx.x] = ws[0] + ws[1] + ws[2] + ws[3];
}

__global__ void bscan_k(const int* __restrict__ bsum, int* __restrict__ boff,
                        int* __restrict__ row_ptr_end, int nb) {
    __shared__ int s[256];
    int t = threadIdx.x;
    int v = (t < nb) ? bsum[t] : 0;
    s[t] = v;
    __syncthreads();
    for (int off = 1; off < 256; off <<= 1) {
        int u = (t >= off) ? s[t - off] : 0;
        __syncthreads();
        s[t] += u;
        __syncthreads();
    }
    if (t < nb) boff[t] = s[t] - v;        // exclusive
    if (t == 255) *row_ptr_end = s[255];   // total -> row_ptr[n]
}

// scan + fused degree-norm (dis only; dinv folded away algebraically)
__global__ void scan3_k(const int* __restrict__ cnt, const int* __restrict__ boff,
                        int* __restrict__ row_ptr, float* __restrict__ dis, int n) {
    __shared__ int s[256];
    int i = blockIdx.x * 256 + threadIdx.x;
    int t = threadIdx.x;
    int v = (i < n) ? cnt[i] : 0;
    s[t] = v;
    __syncthreads();
    for (int off = 1; off < 256; off <<= 1) {
        int u = (t >= off) ? s[t - off] : 0;
        __syncthreads();
        s[t] += u;
        __syncthreads();
    }
    if (i < n) {
        row_ptr[i] = boff[blockIdx.x] + s[t] - v;
        dis[i] = rsqrtf((float)v + 1.0f);
    }
}

// ---------------- P3: per-bucket CSR scatter via LDS window (coalesced dump) ----------------
__global__ __launch_bounds__(256) void csr_k(const int2* __restrict__ ebuf,
                                             const int* __restrict__ bcnt,
                                             const int* __restrict__ row_ptr,
                                             int* __restrict__ col, int n) {
    __shared__ int rp_l[257];
    __shared__ int cur[256];
    __shared__ int win[CAP];
    int b = blockIdx.x, tid = threadIdx.x;
    int node0 = b * 256;
    for (int i = tid; i < 257; i += 256) {
        int nd = node0 + i; if (nd > n) nd = n;
        rp_l[i] = row_ptr[nd];
    }
    cur[tid] = 0;
    __syncthreads();
    int base0 = rp_l[0];
    int m = bcnt[b]; if (m > CAP) m = CAP;

    for (int i = tid; i < m; i += 256) {
        int2 ed = ebuf[(size_t)b * CAP + i];
        int ll = ed.y & 255;
        int pos = rp_l[ll] + atomicAdd(&cur[ll], 1) - base0;
        win[pos] = ed.x;
    }
    __syncthreads();
    for (int i = tid; i < m; i += 256) col[base0 + i] = win[i];
}

// ---------------- canonicalize: wave-per-row sort (wide grid) ----------------
__global__ __launch_bounds__(256) void rowsort_k(const int* __restrict__ rp,
                                                 int* __restrict__ col, int n) {
    int node = blockIdx.x * 4 + (threadIdx.x >> 6);
    if (node >= n) return;
    int lane = threadIdx.x & 63;
    int beg = rp[node], end = rp[node + 1];
    int len = end - beg;
    if (len <= 1) return;
    if (len <= 64) {
        int v = (lane < len) ? col[beg + lane] : 0x7fffffff;
#pragma unroll
        for (int k = 2; k <= 64; k <<= 1)
#pragma unroll
            for (int j = k >> 1; j > 0; j >>= 1) {
                int other = __shfl_xor(v, j);
                bool up    = (lane & k) == 0;
                bool small = (lane & j) == 0;
                v = (small == up) ? min(v, other) : max(v, other);
            }
        if (lane < len) col[beg + lane] = v;
    } else if (lane == 0) {     // rare tail: serial insertion sort
        for (int i = beg + 1; i < end; ++i) {
            int key = col[i]; int j = i - 1;
            while (j >= beg && col[j] > key) { col[j + 1] = col[j]; --j; }
            col[j + 1] = key;
        }
    }
}

// ---- fp32 -> bf16 (RTNE) ----
__device__ inline ushort f2bf(float f) {
    unsigned u = __float_as_uint(f);
    unsigned rounding = 0x7fffu + ((u >> 16) & 1u);
    return (ushort)((u + rounding) >> 16);
}
__device__ inline float bf_lo(uint v) { return __uint_as_float(v << 16); }
__device__ inline float bf_hi(uint v) { return __uint_as_float(v & 0xffff0000u); }
__device__ inline short8 cvt8(float4 f0, float4 f1) {
    short8 r;
    r[0] = (short)f2bf(f0.x); r[1] = (short)f2bf(f0.y);
    r[2] = (short)f2bf(f0.z); r[3] = (short)f2bf(f0.w);
    r[4] = (short)f2bf(f1.x); r[5] = (short)f2bf(f1.y);
    r[6] = (short)f2bf(f1.z); r[7] = (short)f2bf(f1.w);
    return r;
}

// ---------------- all three W -> Wt bf16, one launch; also zero hb pad row N ----------------
__global__ void wtrans_all_k(const float* __restrict__ W0, const float* __restrict__ W1,
                             const float* __restrict__ W2, ushort* __restrict__ Wt0,
                             ushort* __restrict__ Wt1, ushort* __restrict__ Wt2,
                             uint* __restrict__ hb_padrow) {
    int i = blockIdx.x * 256 + threadIdx.x;   // 0..65535
    if (i < 64) hb_padrow[i] = 0;             // zero row N of hb (gather target for pad slots)
    const float* W; ushort* Wt; int K, j;
    if (i < 32768)      { W = W0; Wt = Wt0; K = 256; j = i; }
    else if (i < 49152) { W = W1; Wt = Wt1; K = 128; j = i - 32768; }
    else                { W = W2; Wt = Wt2; K = 128; j = i - 49152; }
    int k = j >> 7, n = j & 127;
    Wt[(size_t)n * K + k] = f2bf(W[j]);
}

// ---------------- MFMA GEMM: LDS-staged A tile, register-resident B ----------------
// tile = 64 rows x 128 cols, 4 waves (wave w owns cols w*32..w*32+31).
// A tile staged to LDS with XOR-swizzle (granule ^= row&7) to kill the
// row-stride bank collision on ds_read_b128. Epilogue scales by dis[row]:
// H = dis * (A W) in bf16.
template<int K, bool AF32>
__global__ __launch_bounds__(256) void gemm_lds_k(const void* __restrict__ Ap,
                                                  const ushort* __restrict__ Bt, // [128][K]
                                                  const float* __restrict__ dis,
                                                  ushort* __restrict__ H,        // [(M+1)][128]
                                                  int M) {
    constexpr int T  = K / 32;                 // MFMA k-steps
    constexpr int EB = AF32 ? 4 : 2;           // element bytes
    constexpr int RS = K * EB;                 // row stride bytes (256/512/1024)
    constexpr int NL = (64 * RS) / 4096;       // staging iters (256 thr x 16B)
    __shared__ char As[64 * RS];

    int tid = threadIdx.x;
    int w = tid >> 6, l = tid & 63, lr = l & 15, hi = l >> 4;
    int cBase = w * 32;

    // B-fragments register-resident (2 col-blocks x T)
    short8 b[2][T];
#pragma unroll
    for (int c = 0; c < 2; ++c)
#pragma unroll
        for (int t = 0; t < T; ++t)
            b[c][t] = *(const short8*)&Bt[(size_t)(cBase + c * 16 + lr) * K + t * 32 + hi * 8];

    int r0 = blockIdx.x * 64;
    const char* gbase = (const char*)Ap + (size_t)r0 * RS;

    // stage A tile: coalesced global read, swizzled LDS write
#pragma unroll
    for (int i = 0; i < NL; ++i) {
        int L   = i * 4096 + tid * 16;
        int row = L / RS;
        int cb  = (L % RS) >> 4;
        const char* srcp = (r0 + row < M) ? (gbase + (size_t)row * RS + ((size_t)cb << 4))
                                          : gbase;           // tail clamp (masked at store)
        uint4 v = *(const uint4*)srcp;
        *(uint4*)&As[row * RS + ((cb ^ (row & 7)) << 4)] = v;
    }
    __syncthreads();

    f32x4 acc[4][2];
#pragma unroll
    for (int rb = 0; rb < 4; ++rb)
#pragma unroll
        for (int c = 0; c < 2; ++c) acc[rb][c] = (f32x4){0.f, 0.f, 0.f, 0.f};

#pragma unroll
    for (int rb = 0; rb < 4; ++rb) {
        int row = rb * 16 + lr;
        int s = row & 7;
        const char* rbase = &As[row * RS];
#pragma unroll
        for (int t = 0; t < T; ++t) {
            short8 a;
            if constexpr (AF32) {
                int cb0 = t * 8 + hi * 2;
                float4 f0 = *(const float4*)(rbase + ((cb0 ^ s) << 4));
                float4 f1 = *(const float4*)(rbase + (((cb0 + 1) ^ s) << 4));
                a = cvt8(f0, f1);
            } else {
                int cb0 = t * 4 + hi;
                a = *(const short8*)(rbase + ((cb0 ^ s) << 4));
            }
#pragma unroll
            for (int c = 0; c < 2; ++c)
                acc[rb][c] = __builtin_amdgcn_mfma_f32_16x16x32_bf16(a, b[c][t], acc[rb][c], 0, 0, 0);
        }
    }

    // epilogue: dis-scale + bf16 store
#pragma unroll
    for (int rb = 0; rb < 4; ++rb) {
#pragma unroll
        for (int j = 0; j < 4; ++j) {
            int r = r0 + rb * 16 + hi * 4 + j;
            if (r < M) {
                float d = dis[r];
#pragma unroll
                for (int c = 0; c < 2; ++c)
                    H[(size_t)r * 128 + cBase + c * 16 + lr] = f2bf(acc[rb][c][j] * d);
            }
        }
    }
}

// ---------------- aggregate: relu(dis[n]*(sum_e hs[s] + hs[n]) + b) ----------------
// hs is pre-scaled by dis in the GEMM epilogue; pad slots gather the zero row N.
// 8 slots x 4 lane-groups = 32 edges in flight per iteration.
template<bool LAST>
__global__ __launch_bounds__(256) void aggregate_k(const ushort* __restrict__ hs,
                                                   const int* __restrict__ row_ptr,
                                                   const int* __restrict__ col,
                                                   const float* __restrict__ dis,
                                                   const float* __restrict__ bias,
                                                   ushort* __restrict__ act,
                                                   float* __restrict__ out, int n) {
    int node = blockIdx.x * 4 + (threadIdx.x >> 6);
    if (node >= n) return;
    int lane = threadIdx.x & 63;
    int g  = lane >> 4;          // edge-slot group 0..3
    int cl = lane & 15;          // column block: cols [8*cl, 8*cl+8)
    const char* base = (const char*)hs + (cl << 4);

    float ax[8];
#pragma unroll
    for (int j = 0; j < 8; ++j) ax[j] = 0.f;

    int beg = row_ptr[node], end = row_ptr[node + 1];
    for (int e = beg; e < end; e += 32) {
        int s[8];
#pragma unroll
        for (int q = 0; q < 8; ++q) {
            int idx = e + q * 4 + g;
            s[q] = (idx < end) ? col[idx] : N_NODES;   // pad -> zero row
        }
        uint4 u[8];
#pragma unroll
        for (int q = 0; q < 8; ++q)
            u[q] = *(const uint4*)(base + ((size_t)s[q] << 8));
#pragma unroll
        for (int q = 0; q < 8; ++q) {
            ax[0] += bf_lo(u[q].x); ax[1] += bf_hi(u[q].x);
            ax[2] += bf_lo(u[q].y); ax[3] += bf_hi(u[q].y);
            ax[4] += bf_lo(u[q].z); ax[5] += bf_hi(u[q].z);
            ax[6] += bf_lo(u[q].w); ax[7] += bf_hi(u[q].w);
        }
    }
#pragma unroll
    for (int j = 0; j < 8; ++j) {
        ax[j] += __shfl_xor(ax[j], 16);
        ax[j] += __shfl_xor(ax[j], 32);
    }
    if (g == 0) {
        float dn = dis[node];
        uint4 un = *(const uint4*)(base + ((size_t)node << 8));
        float hsn[8] = {bf_lo(un.x), bf_hi(un.x), bf_lo(un.y), bf_hi(un.y),
                        bf_lo(un.z), bf_hi(un.z), bf_lo(un.w), bf_hi(un.w)};
        int c0 = cl * 8;
        float4 bv0 = *(const float4*)&bias[c0];
        float4 bv1 = *(const float4*)&bias[c0 + 4];
        float bb[8] = {bv0.x, bv0.y, bv0.z, bv0.w, bv1.x, bv1.y, bv1.z, bv1.w};
        float o[8];
#pragma unroll
        for (int j = 0; j < 8; ++j)
            o[j] = fmaxf((ax[j] + hsn[j]) * dn + bb[j], 0.f);
        if (LAST) {
            *(float4*)&out[(size_t)node * D_HID + c0]     = make_float4(o[0], o[1], o[2], o[3]);
            *(float4*)&out[(size_t)node * D_HID + c0 + 4] = make_float4(o[4], o[5], o[6], o[7]);
        } else {
            uint4 p;
            p.x = (uint)f2bf(o[0]) | ((uint)f2bf(o[1]) << 16);
            p.y = (uint)f2bf(o[2]) | ((uint)f2bf(o[3]) << 16);
            p.z = (uint)f2bf(o[4]) | ((uint)f2bf(o[5]) << 16);
            p.w = (uint)f2bf(o[6]) | ((uint)f2bf(o[7]) << 16);
            *(uint4*)((char*)act + ((size_t)node << 8) + (cl << 4)) = p;
        }
    }
}

extern "C" void kernel_launch(void* const* d_in, const int* in_sizes, int n_in,
                              void* d_out, int out_size, void* d_ws, size_t ws_size,
                              hipStream_t stream) {
    const float* x  = (const float*)d_in[0];
    const int*   ei = (const int*)d_in[1];
    const float* W0 = (const float*)d_in[2];
    const float* b0 = (const float*)d_in[3];
    const float* W1 = (const float*)d_in[4];
    const float* b1 = (const float*)d_in[5];
    const float* W2 = (const float*)d_in[6];
    const float* b2 = (const float*)d_in[7];
    float* out = (float*)d_out;

    const int N = N_NODES, E = N_EDGES;
    const int* src = ei;
    const int* dst = ei + E;

    char* w = (char*)d_ws;
    size_t off = 0;
    auto alloc = [&](size_t bytes) {
        size_t o = off;
        off += (bytes + 255) & ~(size_t)255;
        return o;
    };
    int*    cnt    = (int*)(w + alloc((size_t)N * 4));
    int*    bcur   = (int*)(w + alloc((size_t)NB * 4));
    float*  dis    = (float*)(w + alloc((size_t)N * 4));
    int*    rp     = (int*)(w + alloc((size_t)(N + 1) * 4));
    int*    bsum   = (int*)(w + alloc((size_t)SCAN_NB * 4));
    int*    boff   = (int*)(w + alloc((size_t)SCAN_NB * 4));
    int*    col    = (int*)(w + alloc((size_t)E * 4));
    int2*   ebuf   = (int2*)(w + alloc((size_t)NB * CAP * 8));
    ushort* hb     = (ushort*)(w + alloc((size_t)(N + 1) * D_HID * 2));  // +1 zero pad row
    ushort* act    = (ushort*)(w + alloc((size_t)N * D_HID * 2));
    ushort* Wt0    = (ushort*)(w + alloc((size_t)128 * 256 * 2));
    ushort* Wt1    = (ushort*)(w + alloc((size_t)128 * 128 * 2));
    ushort* Wt2    = (ushort*)(w + alloc((size_t)128 * 128 * 2));
    (void)ws_size; (void)n_in; (void)in_sizes; (void)out_size;

    hipMemsetAsync(bcur, 0, (size_t)NB * 4, stream);

    part_k<<<P1_BLOCKS, 256, 0, stream>>>(src, dst, bcur, ebuf, E);
    bucket_cnt_k<<<NB, 256, 0, stream>>>(ebuf, bcur, cnt, N);
    bsum_k<<<SCAN_NB, 256, 0, stream>>>(cnt, bsum, N);
    bscan_k<<<1, 256, 0, stream>>>(bsum, boff, rp + N, SCAN_NB);
    scan3_k<<<SCAN_NB, 256, 0, stream>>>(cnt, boff, rp, dis, N);
    csr_k<<<NB, 256, 0, stream>>>(ebuf, bcur, rp, col, N);
    rowsort_k<<<(N + 3) / 4, 256, 0, stream>>>(rp, col, N);   // canonical order

    wtrans_all_k<<<256, 256, 0, stream>>>(W0, W1, W2, Wt0, Wt1, Wt2,
                                          (uint*)(hb + (size_t)N * D_HID));

    int nt64 = (N + 63) / 64;   // 782 row-tiles
    int agg_grid = (N + 3) / 4;

    // layer 0
    gemm_lds_k<256, true><<<nt64, 256, 0, stream>>>(x, Wt0, dis, hb, N);
    aggregate_k<false><<<agg_grid, 256, 0, stream>>>(hb, rp, col, dis, b0, act, out, N);
    // layer 1
    gemm_lds_k<128, false><<<nt64, 256, 0, stream>>>(act, Wt1, dis, hb, N);
    aggregate_k<false><<<agg_grid, 256, 0, stream>>>(hb, rp, col, dis, b1, act, out, N);
    // layer 2
    gemm_lds_k<128, false><<<nt64, 256, 0, stream>>>(act, Wt2, dis, hb, N);
    aggregate_k<true><<<agg_grid, 256, 0, stream>>>(hb, rp, col, dis, b2, act, out, N);
}

// Round 13
// 230.580 us; speedup vs baseline: 1.1283x; 1.0073x over previous
//
#include <hip/hip_runtime.h>

#define N_NODES 50000
#define N_EDGES 800000
#define D_HID   128

typedef unsigned int uint;
typedef unsigned short ushort;
typedef __attribute__((ext_vector_type(8))) short short8;
typedef __attribute__((ext_vector_type(4))) float f32x4;

#define NB       196                       // dst buckets of 256 nodes
#define CAP      6144                      // per-bucket ebuf capacity
#define P1_BLOCKS 200
#define P1_CHUNK  4000                     // 200 * 4000 = 800000 exactly

// ---------------- P1: partition edges into dst-range buckets ----------------
__global__ __launch_bounds__(256) void part_k(const int* __restrict__ src,
                                              const int* __restrict__ dst,
                                              int* __restrict__ bcur,
                                              int2* __restrict__ ebuf, int e) {
    __shared__ int hist[NB];
    __shared__ int base[NB];
    int tid = threadIdx.x;
    if (tid < NB) hist[tid] = 0;
    __syncthreads();

    int e0 = blockIdx.x * P1_CHUNK;
    int2 ed[16];
    bool val[16];
#pragma unroll
    for (int i = 0; i < 16; ++i) {
        int o = i * 256 + tid;
        int idx = e0 + o;
        val[i] = (o < P1_CHUNK) && (idx < e);
        if (val[i]) {
            ed[i] = make_int2(src[idx], dst[idx]);
            atomicAdd(&hist[ed[i].y >> 8], 1);
        }
    }
    __syncthreads();
    if (tid < NB && hist[tid] > 0) base[tid] = atomicAdd(&bcur[tid], hist[tid]);
    __syncthreads();
    if (tid < NB) hist[tid] = 0;
    __syncthreads();
#pragma unroll
    for (int i = 0; i < 16; ++i) {
        if (val[i]) {
            int bk = ed[i].y >> 8;
            int o  = base[bk] + atomicAdd(&hist[bk], 1);
            if (o < CAP) ebuf[(size_t)bk * CAP + o] = ed[i];
        }
    }
}

// ---------------- scan of per-bucket totals (bcur) -> boff, row_ptr[N] ----------------
__global__ void bscan196_k(const int* __restrict__ bcur, int* __restrict__ boff,
                           int* __restrict__ row_ptr_end) {
    __shared__ int s[256];
    int t = threadIdx.x;
    int v = (t < NB) ? bcur[t] : 0;
    s[t] = v;
    __syncthreads();
    for (int off = 1; off < 256; off <<= 1) {
        int u = (t >= off) ? s[t - off] : 0;
        __syncthreads();
        s[t] += u;
        __syncthreads();
    }
    if (t < NB) boff[t] = s[t] - v;        // exclusive
    if (t == 255) *row_ptr_end = s[255];   // total -> row_ptr[n]
}

// ---------------- per-bucket count + LDS scan -> row_ptr + dis ----------------
__global__ __launch_bounds__(256) void cntscan_k(const int2* __restrict__ ebuf,
                                                 const int* __restrict__ bcnt,
                                                 const int* __restrict__ boff,
                                                 int* __restrict__ row_ptr,
                                                 float* __restrict__ dis, int n) {
    __shared__ int c[256];
    __shared__ int s[256];
    int b = blockIdx.x, tid = threadIdx.x;
    c[tid] = 0;
    __syncthreads();
    int m = bcnt[b]; if (m > CAP) m = CAP;
    for (int i = tid; i < m; i += 256)
        atomicAdd(&c[ebuf[(size_t)b * CAP + i].y & 255], 1);
    __syncthreads();
    int v = c[tid];
    s[tid] = v;
    __syncthreads();
    for (int off = 1; off < 256; off <<= 1) {
        int u = (tid >= off) ? s[tid - off] : 0;
        __syncthreads();
        s[tid] += u;
        __syncthreads();
    }
    int node = b * 256 + tid;
    if (node < n) {
        row_ptr[node] = boff[b] + s[tid] - v;
        dis[node] = rsqrtf((float)v + 1.0f);
    }
}

// ---------------- P3: per-bucket CSR scatter via LDS window (coalesced dump) ----------------
// stores src<<8 (pre-shifted byte offsets for the aggregate's gathers)
__global__ __launch_bounds__(256) void csr_k(const int2* __restrict__ ebuf,
                                             const int* __restrict__ bcnt,
                                             const int* __restrict__ row_ptr,
                                             int* __restrict__ col, int n) {
    __shared__ int rp_l[257];
    __shared__ int cur[256];
    __shared__ int win[CAP];
    int b = blockIdx.x, tid = threadIdx.x;
    int node0 = b * 256;
    for (int i = tid; i < 257; i += 256) {
        int nd = node0 + i; if (nd > n) nd = n;
        rp_l[i] = row_ptr[nd];
    }
    cur[tid] = 0;
    __syncthreads();
    int base0 = rp_l[0];
    int m = bcnt[b]; if (m > CAP) m = CAP;

    for (int i = tid; i < m; i += 256) {
        int2 ed = ebuf[(size_t)b * CAP + i];
        int ll = ed.y & 255;
        int pos = rp_l[ll] + atomicAdd(&cur[ll], 1) - base0;
        win[pos] = ed.x << 8;                       // pre-shifted
    }
    __syncthreads();
    for (int i = tid; i < m; i += 256) col[base0 + i] = win[i];
}

// ---------------- canonicalize: wave-per-row sort (wide grid) ----------------
__global__ __launch_bounds__(256) void rowsort_k(const int* __restrict__ rp,
                                                 int* __restrict__ col, int n) {
    int node = blockIdx.x * 4 + (threadIdx.x >> 6);
    if (node >= n) return;
    int lane = threadIdx.x & 63;
    int beg = rp[node], end = rp[node + 1];
    int len = end - beg;
    if (len <= 1) return;
    if (len <= 64) {
        int v = (lane < len) ? col[beg + lane] : 0x7fffffff;
#pragma unroll
        for (int k = 2; k <= 64; k <<= 1)
#pragma unroll
            for (int j = k >> 1; j > 0; j >>= 1) {
                int other = __shfl_xor(v, j);
                bool up    = (lane & k) == 0;
                bool small = (lane & j) == 0;
                v = (small == up) ? min(v, other) : max(v, other);
            }
        if (lane < len) col[beg + lane] = v;
    } else if (lane == 0) {     // rare tail: serial insertion sort
        for (int i = beg + 1; i < end; ++i) {
            int key = col[i]; int j = i - 1;
            while (j >= beg && col[j] > key) { col[j + 1] = col[j]; --j; }
            col[j + 1] = key;
        }
    }
}

// ---- fp32 -> bf16 (RTNE) ----
__device__ inline ushort f2bf(float f) {
    unsigned u = __float_as_uint(f);
    unsigned rounding = 0x7fffu + ((u >> 16) & 1u);
    return (ushort)((u + rounding) >> 16);
}
__device__ inline float bf_lo(uint v) { return __uint_as_float(v << 16); }
__device__ inline float bf_hi(uint v) { return __uint_as_float(v & 0xffff0000u); }
__device__ inline short8 cvt8(float4 f0, float4 f1) {
    short8 r;
    r[0] = (short)f2bf(f0.x); r[1] = (short)f2bf(f0.y);
    r[2] = (short)f2bf(f0.z); r[3] = (short)f2bf(f0.w);
    r[4] = (short)f2bf(f1.x); r[5] = (short)f2bf(f1.y);
    r[6] = (short)f2bf(f1.z); r[7] = (short)f2bf(f1.w);
    return r;
}

// async global -> LDS (16B per lane; LDS dest = wave-uniform base + lane*16)
__device__ inline void gload16(const void* g, void* l) {
    __builtin_amdgcn_global_load_lds(
        (const __attribute__((address_space(1))) uint*)g,
        (__attribute__((address_space(3))) uint*)l, 16, 0, 0);
}

// ---------------- all three W -> Wt bf16, one launch; also zero hb pad row N ----------------
__global__ void wtrans_all_k(const float* __restrict__ W0, const float* __restrict__ W1,
                             const float* __restrict__ W2, ushort* __restrict__ Wt0,
                             ushort* __restrict__ Wt1, ushort* __restrict__ Wt2,
                             uint* __restrict__ hb_padrow) {
    int i = blockIdx.x * 256 + threadIdx.x;   // 0..65535
    if (i < 64) hb_padrow[i] = 0;             // zero row N of hb (gather target for pad slots)
    const float* W; ushort* Wt; int K, j;
    if (i < 32768)      { W = W0; Wt = Wt0; K = 256; j = i; }
    else if (i < 49152) { W = W1; Wt = Wt1; K = 128; j = i - 32768; }
    else                { W = W2; Wt = Wt2; K = 128; j = i - 49152; }
    int k = j >> 7, n = j & 127;
    Wt[(size_t)n * K + k] = f2bf(W[j]);
}

// ---------------- MFMA GEMM: global_load_lds staged A tile, register-resident B ----------------
// LDS layout is LINEAR; the XOR-swizzle is applied to the GLOBAL source address
// (LDS slot [row][cb] holds A[row][cb ^ (row&7)]), so the ds_read side is
// bank-conflict-free and gload_lds's uniform-base+lane*16 constraint is met.
// 4 waves, wave w owns cols w*32..w*32+31. Epilogue: H = dis * (A W) in bf16.
template<int K, int ROWS, bool AF32>
__global__ __launch_bounds__(256) void gemm_lds_k(const void* __restrict__ Ap,
                                                  const ushort* __restrict__ Bt, // [128][K]
                                                  const float* __restrict__ dis,
                                                  ushort* __restrict__ H,        // [(M+1)][128]
                                                  int M) {
    constexpr int T  = K / 32;                 // MFMA k-steps
    constexpr int EB = AF32 ? 4 : 2;           // element bytes
    constexpr int RS = K * EB;                 // row stride bytes
    constexpr int NI = (ROWS * RS) / 4096;     // staging iters (4 waves x 1KB)
    __shared__ char As[ROWS * RS];

    int tid = threadIdx.x;
    int w = tid >> 6, l = tid & 63, lr = l & 15, hi = l >> 4;
    int cBase = w * 32;

    // B-fragments register-resident (2 col-blocks x T)
    short8 b[2][T];
#pragma unroll
    for (int c = 0; c < 2; ++c)
#pragma unroll
        for (int t = 0; t < T; ++t)
            b[c][t] = *(const short8*)&Bt[(size_t)(cBase + c * 16 + lr) * K + t * 32 + hi * 8];

    int r0 = blockIdx.x * ROWS;
    const char* gbase = (const char*)Ap + (size_t)r0 * RS;

    // stage A tile: pre-swizzled global source -> linear LDS via global_load_lds
#pragma unroll
    for (int i = 0; i < NI; ++i) {
        int L0  = (i * 4 + w) * 1024;          // wave-uniform LDS base
        int L   = L0 + l * 16;
        int row = L / RS;
        int cb  = (L % RS) >> 4;
        int gb  = (cb ^ (row & 7)) << 4;
        int grow = (r0 + row < M) ? row : 0;   // tail clamp (masked at store)
        gload16(gbase + (size_t)grow * RS + gb, &As[L0]);
    }
    __syncthreads();

    f32x4 acc[ROWS / 16][2];
#pragma unroll
    for (int rb = 0; rb < ROWS / 16; ++rb)
#pragma unroll
        for (int c = 0; c < 2; ++c) acc[rb][c] = (f32x4){0.f, 0.f, 0.f, 0.f};

#pragma unroll
    for (int rb = 0; rb < ROWS / 16; ++rb) {
        int row = rb * 16 + lr;
        int s = row & 7;
        const char* rbase = &As[row * RS];
#pragma unroll
        for (int t = 0; t < T; ++t) {
            short8 a;
            if constexpr (AF32) {
                int cb0 = t * 8 + hi * 2;
                float4 f0 = *(const float4*)(rbase + ((cb0 ^ s) << 4));
                float4 f1 = *(const float4*)(rbase + (((cb0 + 1) ^ s) << 4));
                a = cvt8(f0, f1);
            } else {
                int cb0 = t * 4 + hi;
                a = *(const short8*)(rbase + ((cb0 ^ s) << 4));
            }
#pragma unroll
            for (int c = 0; c < 2; ++c)
                acc[rb][c] = __builtin_amdgcn_mfma_f32_16x16x32_bf16(a, b[c][t], acc[rb][c], 0, 0, 0);
        }
    }

    // epilogue: dis-scale + bf16 store
#pragma unroll
    for (int rb = 0; rb < ROWS / 16; ++rb) {
#pragma unroll
        for (int j = 0; j < 4; ++j) {
            int r = r0 + rb * 16 + hi * 4 + j;
            if (r < M) {
                float d = dis[r];
#pragma unroll
                for (int c = 0; c < 2; ++c)
                    H[(size_t)r * 128 + cBase + c * 16 + lr] = f2bf(acc[rb][c][j] * d);
            }
        }
    }
}

// ---------------- aggregate: relu(dis[n]*(sum_e hs[s] + hs[n]) + b) ----------------
// hs pre-scaled by dis in the GEMM epilogue; col holds pre-shifted byte offsets;
// pad slots gather the zero row N. 8 slots x 4 lane-groups = 32 edges in flight.
template<bool LAST>
__global__ __launch_bounds__(256) void aggregate_k(const ushort* __restrict__ hs,
                                                   const int* __restrict__ row_ptr,
                                                   const int* __restrict__ col,
                                                   const float* __restrict__ dis,
                                                   const float* __restrict__ bias,
                                                   ushort* __restrict__ act,
                                                   float* __restrict__ out, int n) {
    int node = blockIdx.x * 4 + (threadIdx.x >> 6);
    if (node >= n) return;
    int lane = threadIdx.x & 63;
    int g  = lane >> 4;          // edge-slot group 0..3
    int cl = lane & 15;          // column block: cols [8*cl, 8*cl+8)
    const char* base = (const char*)hs + (cl << 4);

    float ax[8];
#pragma unroll
    for (int j = 0; j < 8; ++j) ax[j] = 0.f;

    int beg = row_ptr[node], end = row_ptr[node + 1];
    for (int e = beg; e < end; e += 32) {
        int s[8];
#pragma unroll
        for (int q = 0; q < 8; ++q) {
            int idx = e + q * 4 + g;
            s[q] = (idx < end) ? col[idx] : (N_NODES << 8);   // pad -> zero row
        }
        uint4 u[8];
#pragma unroll
        for (int q = 0; q < 8; ++q)
            u[q] = *(const uint4*)(base + (size_t)(uint)s[q]);
#pragma unroll
        for (int q = 0; q < 8; ++q) {
            ax[0] += bf_lo(u[q].x); ax[1] += bf_hi(u[q].x);
            ax[2] += bf_lo(u[q].y); ax[3] += bf_hi(u[q].y);
            ax[4] += bf_lo(u[q].z); ax[5] += bf_hi(u[q].z);
            ax[6] += bf_lo(u[q].w); ax[7] += bf_hi(u[q].w);
        }
    }
#pragma unroll
    for (int j = 0; j < 8; ++j) {
        ax[j] += __shfl_xor(ax[j], 16);
        ax[j] += __shfl_xor(ax[j], 32);
    }
    if (g == 0) {
        float dn = dis[node];
        uint4 un = *(const uint4*)(base + ((size_t)node << 8));
        float hsn[8] = {bf_lo(un.x), bf_hi(un.x), bf_lo(un.y), bf_hi(un.y),
                        bf_lo(un.z), bf_hi(un.z), bf_lo(un.w), bf_hi(un.w)};
        int c0 = cl * 8;
        float4 bv0 = *(const float4*)&bias[c0];
        float4 bv1 = *(const float4*)&bias[c0 + 4];
        float bb[8] = {bv0.x, bv0.y, bv0.z, bv0.w, bv1.x, bv1.y, bv1.z, bv1.w};
        float o[8];
#pragma unroll
        for (int j = 0; j < 8; ++j)
            o[j] = fmaxf((ax[j] + hsn[j]) * dn + bb[j], 0.f);
        if (LAST) {
            *(float4*)&out[(size_t)node * D_HID + c0]     = make_float4(o[0], o[1], o[2], o[3]);
            *(float4*)&out[(size_t)node * D_HID + c0 + 4] = make_float4(o[4], o[5], o[6], o[7]);
        } else {
            uint4 p;
            p.x = (uint)f2bf(o[0]) | ((uint)f2bf(o[1]) << 16);
            p.y = (uint)f2bf(o[2]) | ((uint)f2bf(o[3]) << 16);
            p.z = (uint)f2bf(o[4]) | ((uint)f2bf(o[5]) << 16);
            p.w = (uint)f2bf(o[6]) | ((uint)f2bf(o[7]) << 16);
            *(uint4*)((char*)act + ((size_t)node << 8) + (cl << 4)) = p;
        }
    }
}

extern "C" void kernel_launch(void* const* d_in, const int* in_sizes, int n_in,
                              void* d_out, int out_size, void* d_ws, size_t ws_size,
                              hipStream_t stream) {
    const float* x  = (const float*)d_in[0];
    const int*   ei = (const int*)d_in[1];
    const float* W0 = (const float*)d_in[2];
    const float* b0 = (const float*)d_in[3];
    const float* W1 = (const float*)d_in[4];
    const float* b1 = (const float*)d_in[5];
    const float* W2 = (const float*)d_in[6];
    const float* b2 = (const float*)d_in[7];
    float* out = (float*)d_out;

    const int N = N_NODES, E = N_EDGES;
    const int* src = ei;
    const int* dst = ei + E;

    char* w = (char*)d_ws;
    size_t off = 0;
    auto alloc = [&](size_t bytes) {
        size_t o = off;
        off += (bytes + 255) & ~(size_t)255;
        return o;
    };
    int*    bcur   = (int*)(w + alloc((size_t)NB * 4));
    float*  dis    = (float*)(w + alloc((size_t)N * 4));
    int*    rp     = (int*)(w + alloc((size_t)(N + 1) * 4));
    int*    boff   = (int*)(w + alloc((size_t)NB * 4));
    int*    col    = (int*)(w + alloc((size_t)E * 4));
    int2*   ebuf   = (int2*)(w + alloc((size_t)NB * CAP * 8));
    ushort* hb     = (ushort*)(w + alloc((size_t)(N + 1) * D_HID * 2));  // +1 zero pad row
    ushort* act    = (ushort*)(w + alloc((size_t)N * D_HID * 2));
    ushort* Wt0    = (ushort*)(w + alloc((size_t)128 * 256 * 2));
    ushort* Wt1    = (ushort*)(w + alloc((size_t)128 * 128 * 2));
    ushort* Wt2    = (ushort*)(w + alloc((size_t)128 * 128 * 2));
    (void)ws_size; (void)n_in; (void)in_sizes; (void)out_size;

    hipMemsetAsync(bcur, 0, (size_t)NB * 4, stream);

    part_k<<<P1_BLOCKS, 256, 0, stream>>>(src, dst, bcur, ebuf, E);
    bscan196_k<<<1, 256, 0, stream>>>(bcur, boff, rp + N);
    cntscan_k<<<NB, 256, 0, stream>>>(ebuf, bcur, boff, rp, dis, N);
    csr_k<<<NB, 256, 0, stream>>>(ebuf, bcur, rp, col, N);
    rowsort_k<<<(N + 3) / 4, 256, 0, stream>>>(rp, col, N);   // canonical order

    wtrans_all_k<<<256, 256, 0, stream>>>(W0, W1, W2, Wt0, Wt1, Wt2,
                                          (uint*)(hb + (size_t)N * D_HID));

    int g32 = (N + 31) / 32;    // 1563 (layer 0, 32-row tiles)
    int g64 = (N + 63) / 64;    // 782  (layers 1-2, 64-row tiles)
    int agg_grid = (N + 3) / 4;

    // layer 0
    gemm_lds_k<256, 32, true><<<g32, 256, 0, stream>>>(x, Wt0, dis, hb, N);
    aggregate_k<false><<<agg_grid, 256, 0, stream>>>(hb, rp, col, dis, b0, act, out, N);
    // layer 1
    gemm_lds_k<128, 64, false><<<g64, 256, 0, stream>>>(act, Wt1, dis, hb, N);
    aggregate_k<false><<<agg_grid, 256, 0, stream>>>(hb, rp, col, dis, b1, act, out, N);
    // layer 2
    gemm_lds_k<128, 64, false><<<g64, 256, 0, stream>>>(act, Wt2, dis, hb, N);
    aggregate_k<true><<<agg_grid, 256, 0, stream>>>(hb, rp, col, dis, b2, act, out, N);
}